// Round 10
// baseline (126.367 us; speedup 1.0000x reference)
//
#include <hip/hip_runtime.h>

#define SIZE 1024
#define MM 10
#define NTERMS 10

typedef _Float16 f16;
typedef __attribute__((ext_vector_type(8))) _Float16 f16x8;
typedef __attribute__((ext_vector_type(4))) _Float16 f16x4;
typedef __attribute__((ext_vector_type(4))) float    f32x4;
typedef __attribute__((ext_vector_type(2))) int      i2;

__device__ __forceinline__ float4 ldq(const float* p) { return *(const float4*)p; }

#define FMA4F(W, v0, v1, v2, v3)                                     \
    a0 = fmaf((W)[0], (v0), a0); a1 = fmaf((W)[1], (v1), a1);        \
    a2 = fmaf((W)[2], (v2), a2); a3 = fmaf((W)[3], (v3), a3);

// ===========================================================================
// Phase 1: G = A^T (out = x @ G). R7-proven config: 512 blocks x 2 identity
// rows (R9's 1024x1 went coef-bound ~27us; R8's 128x8 went latency-bound 63us;
// 512x2 measured best inside R7's 82us total).
// ===========================================================================
__global__ __launch_bounds__(256, 2)
void precompute_G(const float* __restrict__ diag,
                  const float* __restrict__ subpad,
                  const float* __restrict__ suppad,
                  const float* __restrict__ logit,
                  float* __restrict__ G)
{
    __shared__ float buf[2][2][SIZE];     // 16 KB

    const int tid = threadIdx.x;
    const int s0  = tid * 4;
    const int rowbase = blockIdx.x * 2;   // 512 blocks x 2 rows = 1024

    #pragma unroll
    for (int r = 0; r < 2; ++r) {
        float4 v;
        v.x = (rowbase + r == s0 + 0) ? 1.f : 0.f;
        v.y = (rowbase + r == s0 + 1) ? 1.f : 0.f;
        v.z = (rowbase + r == s0 + 2) ? 1.f : 0.f;
        v.w = (rowbase + r == s0 + 3) ? 1.f : 0.f;
        *(float4*)&buf[0][r][s0] = v;
    }
    __syncthreads();

    int cur = 0;
    for (int t = 0; t < NTERMS; ++t) {
        const int i = NTERMS - 1 - t;

        float lg[MM];
        float mx = -3.4e38f;
        #pragma unroll
        for (int j = 0; j < MM; ++j) { lg[j] = logit[i * MM + j]; mx = fmaxf(mx, lg[j]); }
        float ssum = 0.f;
        #pragma unroll
        for (int j = 0; j < MM; ++j) { lg[j] = __expf(lg[j] - mx); ssum += lg[j]; }
        const float inv = 1.0f / ssum;

        float D[4] = {0.f, 0.f, 0.f, 0.f};
        float Wsb[MM][4], Wsp[MM][4];
        #pragma unroll
        for (int j = 0; j < MM; ++j) {
            const float pj = lg[j] * inv;
            const float4 dg = ldq(diag   + j * SIZE + s0);
            const float4 sb = ldq(subpad + j * SIZE + s0);
            const float4 sp = ldq(suppad + j * SIZE + s0);
            D[0] = fmaf(pj, dg.x, D[0]); D[1] = fmaf(pj, dg.y, D[1]);
            D[2] = fmaf(pj, dg.z, D[2]); D[3] = fmaf(pj, dg.w, D[3]);
            Wsb[j][0] = pj * sb.x; Wsb[j][1] = pj * sb.y;
            Wsb[j][2] = pj * sb.z; Wsb[j][3] = pj * sb.w;
            Wsp[j][0] = pj * sp.x; Wsp[j][1] = pj * sp.y;
            Wsp[j][2] = pj * sp.z; Wsp[j][3] = pj * sp.w;
        }

        const bool last = (t == NTERMS - 1);
        for (int r = 0; r < 2; ++r) {
            const float* row = &buf[cur][r][0];

            const float4 xo = ldq(row + s0);
            float a0 = D[0] * xo.x, a1 = D[1] * xo.y,
                  a2 = D[2] * xo.z, a3 = D[3] * xo.w;

            const float4 xl = ldq(row + (s0 >= 4         ? s0 - 4 : 0));
            const float4 xr = ldq(row + (s0 + 4 <= 1020  ? s0 + 4 : 1020));

            FMA4F(Wsb[9], xl.w, xo.x, xo.y, xo.z)
            FMA4F(Wsp[9], xo.y, xo.z, xo.w, xr.x)
            FMA4F(Wsb[8], xl.z, xl.w, xo.x, xo.y)
            FMA4F(Wsp[8], xo.z, xo.w, xr.x, xr.y)
            FMA4F(Wsb[7], xl.x, xl.y, xl.z, xl.w)
            FMA4F(Wsp[7], xr.x, xr.y, xr.z, xr.w)
            #pragma unroll
            for (int j = 0; j <= 6; ++j) {
                const int d = 512 >> j;
                const float4 xm = ldq(row + (s0 >= d        ? s0 - d : 0));
                const float4 xp = ldq(row + (s0 + d <= 1020 ? s0 + d : 1020));
                FMA4F(Wsb[j], xm.x, xm.y, xm.z, xm.w)
                FMA4F(Wsp[j], xp.x, xp.y, xp.z, xp.w)
            }

            if (last) {
                *(float4*)(G + (long)(rowbase + r) * SIZE + s0) =
                    make_float4(a0, a1, a2, a3);
            } else {
                *(float4*)&buf[cur ^ 1][r][s0] = make_float4(a0, a1, a2, a3);
            }
        }
        __syncthreads();
        cur ^= 1;
    }
}

// ===========================================================================
// Phase 2: Gt[s][k] = (f16) G[k][s]
// ===========================================================================
__global__ __launch_bounds__(256)
void transpose_cast(const float* __restrict__ G, f16* __restrict__ Gt)
{
    __shared__ float tile[64][65];
    const int tid = threadIdx.x;
    const int k0 = blockIdx.x * 64;
    const int s0 = blockIdx.y * 64;
    const int rr = tid >> 4;
    const int cc = (tid & 15) * 4;

    #pragma unroll
    for (int p = 0; p < 4; ++p) {
        const float4 v = ldq(G + (long)(k0 + rr + p * 16) * SIZE + s0 + cc);
        *(float4*)&tile[rr + p * 16][cc] = v;
    }
    __syncthreads();
    #pragma unroll
    for (int p = 0; p < 4; ++p) {
        const int s = rr + p * 16;
        f16x4 h;
        h[0] = (f16)tile[cc + 0][s];
        h[1] = (f16)tile[cc + 1][s];
        h[2] = (f16)tile[cc + 2][s];
        h[3] = (f16)tile[cc + 3][s];
        *(f16x4*)(Gt + (long)(s0 + s) * SIZE + k0 + cc) = h;
    }
}

// ===========================================================================
// Phase 3 (R10 redesign): ZERO-LDS, ZERO-BARRIER GEMM.
// R9 proved the gemm is latency/serialization-bound (FETCH 132->25MB moved
// dur only 63->58; MfmaUtil 10%, all pipes idle): the per-kt
// vmcnt(0)-before-barrier drain put full load latency on the critical path.
// Each wave's A-fragment rows are wave-private, so A is loaded DIRECTLY from
// global (2 x float4 + cvt per frag — same cvt/values/order as the LDS path
// -> bitwise-identical output). No __shared__, no __syncthreads: all 8
// waves/CU run free, counted-vmcnt prefetch (P/Q named-reg double buffer,
// static indexing) hides L2/HBM latency under MFMA. bm-swizzle kept (bid&63)
// so the 8 bn-blocks sharing an x-panel stay on one XCD (FETCH 25MB proven).
// ===========================================================================
#define NKT 32

__device__ __forceinline__ void cvt16(const float4& v0, const float4& v1, f16x8& h) {
    h[0] = (f16)v0.x; h[1] = (f16)v0.y; h[2] = (f16)v0.z; h[3] = (f16)v0.w;
    h[4] = (f16)v1.x; h[5] = (f16)v1.y; h[6] = (f16)v1.z; h[7] = (f16)v1.w;
}

__global__ __launch_bounds__(256, 2)
void gemm_f16(const float* __restrict__ x,
              const f16* __restrict__ Gt,
              float* __restrict__ out)
{
    const int tid  = threadIdx.x;
    const int bm   = blockIdx.x & 63;          // same-bm -> same XCD
    const int bn   = blockIdx.x >> 6;
    const int w    = tid >> 6, lane = tid & 63;
    const int wm   = w >> 1,  wn   = w & 1;
    const int lr   = lane & 15, lk = lane >> 4;

    // A frag rows (wave-private): row = bm*128 + wm*64 + mi*16 + lr, k = lk*8
    const float* arow0 = x + (long)(bm * 128 + wm * 64 +  0 + lr) * 1024 + lk * 8;
    const float* arow1 = arow0 + 16 * 1024;
    const float* arow2 = arow0 + 32 * 1024;
    const float* arow3 = arow0 + 48 * 1024;
    // B frag rows: n = bn*128 + wn*64 + ni*16 + lr, k = lk*8
    const f16* gbase = Gt + (long)(bn * 128 + wn * 64 + lr) * 1024 + lk * 8;

    f32x4 acc[4][4];
    #pragma unroll
    for (int mi = 0; mi < 4; ++mi)
        #pragma unroll
        for (int ni = 0; ni < 4; ++ni)
            acc[mi][ni] = (f32x4){0.f, 0.f, 0.f, 0.f};

    // two named register sets (P = even kt, Q = odd kt) — static indexing only
    float4 P0l, P0h, P1l, P1h, P2l, P2h, P3l, P3h;
    float4 Q0l, Q0h, Q1l, Q1h, Q2l, Q2h, Q3l, Q3h;
    f16x8 gP0, gP1, gP2, gP3;
    f16x8 gQ0, gQ1, gQ2, gQ3;

#define LOADA(S, KT) {                                                \
        const int o = (KT) * 32;                                      \
        S##0l = ldq(arow0 + o); S##0h = ldq(arow0 + o + 4);           \
        S##1l = ldq(arow1 + o); S##1h = ldq(arow1 + o + 4);           \
        S##2l = ldq(arow2 + o); S##2h = ldq(arow2 + o + 4);           \
        S##3l = ldq(arow3 + o); S##3h = ldq(arow3 + o + 4); }
#define LOADB(S, KT) {                                                \
        const f16* gp = gbase + (KT) * 32;                            \
        S##0 = *(const f16x8*)(gp);                                   \
        S##1 = *(const f16x8*)(gp + 16 * 1024);                       \
        S##2 = *(const f16x8*)(gp + 32 * 1024);                       \
        S##3 = *(const f16x8*)(gp + 48 * 1024); }
#define COMP(S, B) {                                                  \
        f16x8 fa;                                                     \
        cvt16(S##0l, S##0h, fa);                                      \
        acc[0][0] = __builtin_amdgcn_mfma_f32_16x16x32_f16(fa, B##0, acc[0][0], 0, 0, 0); \
        acc[0][1] = __builtin_amdgcn_mfma_f32_16x16x32_f16(fa, B##1, acc[0][1], 0, 0, 0); \
        acc[0][2] = __builtin_amdgcn_mfma_f32_16x16x32_f16(fa, B##2, acc[0][2], 0, 0, 0); \
        acc[0][3] = __builtin_amdgcn_mfma_f32_16x16x32_f16(fa, B##3, acc[0][3], 0, 0, 0); \
        cvt16(S##1l, S##1h, fa);                                      \
        acc[1][0] = __builtin_amdgcn_mfma_f32_16x16x32_f16(fa, B##0, acc[1][0], 0, 0, 0); \
        acc[1][1] = __builtin_amdgcn_mfma_f32_16x16x32_f16(fa, B##1, acc[1][1], 0, 0, 0); \
        acc[1][2] = __builtin_amdgcn_mfma_f32_16x16x32_f16(fa, B##2, acc[1][2], 0, 0, 0); \
        acc[1][3] = __builtin_amdgcn_mfma_f32_16x16x32_f16(fa, B##3, acc[1][3], 0, 0, 0); \
        cvt16(S##2l, S##2h, fa);                                      \
        acc[2][0] = __builtin_amdgcn_mfma_f32_16x16x32_f16(fa, B##0, acc[2][0], 0, 0, 0); \
        acc[2][1] = __builtin_amdgcn_mfma_f32_16x16x32_f16(fa, B##1, acc[2][1], 0, 0, 0); \
        acc[2][2] = __builtin_amdgcn_mfma_f32_16x16x32_f16(fa, B##2, acc[2][2], 0, 0, 0); \
        acc[2][3] = __builtin_amdgcn_mfma_f32_16x16x32_f16(fa, B##3, acc[2][3], 0, 0, 0); \
        cvt16(S##3l, S##3h, fa);                                      \
        acc[3][0] = __builtin_amdgcn_mfma_f32_16x16x32_f16(fa, B##0, acc[3][0], 0, 0, 0); \
        acc[3][1] = __builtin_amdgcn_mfma_f32_16x16x32_f16(fa, B##1, acc[3][1], 0, 0, 0); \
        acc[3][2] = __builtin_amdgcn_mfma_f32_16x16x32_f16(fa, B##2, acc[3][2], 0, 0, 0); \
        acc[3][3] = __builtin_amdgcn_mfma_f32_16x16x32_f16(fa, B##3, acc[3][3], 0, 0, 0); }

    // prologue: kt 0 into P
    LOADA(P, 0); LOADB(gP, 0);

    #pragma unroll 1
    for (int kt2 = 0; kt2 < NKT / 2; ++kt2) {
        const int kt = kt2 * 2;
        LOADA(Q, kt + 1); LOADB(gQ, kt + 1);   // prefetch odd step
        COMP(P, gP);                            // compute even step
        if (kt2 < NKT / 2 - 1) {
            LOADA(P, kt + 2); LOADB(gP, kt + 2); // prefetch next even step
        }
        COMP(Q, gQ);                            // compute odd step
    }

    // epilogue: D lane l,q -> row (l>>4)*4+q, col l&15   (R7-verified)
    const long orow0 = (long)bm * 128 + wm * 64 + lk * 4;
    const int  ocol0 = bn * 128 + wn * 64 + lr;
    #pragma unroll
    for (int mi = 0; mi < 4; ++mi)
        #pragma unroll
        for (int ni = 0; ni < 4; ++ni)
            #pragma unroll
            for (int q = 0; q < 4; ++q)
                out[(orow0 + mi * 16 + q) * 1024 + ocol0 + ni * 16] = acc[mi][ni][q];

#undef LOADA
#undef LOADB
#undef COMP
}

// ===========================================================================
// Fallback (ws too small): R6's proven stencil kernel.
// ===========================================================================
#define RPB 16
#define MIX_L(acc, r32, ww) \
    asm("v_fma_mix_f32 %0, %1, %2, %0 op_sel:[0,0,0] op_sel_hi:[1,0,0]" \
        : "+v"(acc) : "v"(r32), "v"(ww))
#define MIX_H(acc, r32, ww) \
    asm("v_fma_mix_f32 %0, %1, %2, %0 op_sel:[1,0,0] op_sel_hi:[1,0,0]" \
        : "+v"(acc) : "v"(r32), "v"(ww))

__global__ __launch_bounds__(256, 2)
void butterfly_h16mix(const float* __restrict__ x,
                      const float* __restrict__ diag,
                      const float* __restrict__ subpad,
                      const float* __restrict__ suppad,
                      const float* __restrict__ logit,
                      float* __restrict__ out)
{
    __shared__ f16 buf[2][RPB][SIZE];
    const int tid = threadIdx.x;
    const int s0  = tid * 4;
    const long rowbase = (long)blockIdx.x * RPB;

    #pragma unroll
    for (int r = 0; r < RPB; ++r) {
        const float4 v = ldq(x + (rowbase + r) * SIZE + s0);
        f16x4 h;
        h[0] = (f16)v.x; h[1] = (f16)v.y; h[2] = (f16)v.z; h[3] = (f16)v.w;
        *(f16x4*)&buf[0][r][s0] = h;
    }
    __syncthreads();

    int cur = 0;
    for (int t = 0; t < NTERMS; ++t) {
        const int i = NTERMS - 1 - t;
        float lg[MM];
        float mx = -3.4e38f;
        #pragma unroll
        for (int j = 0; j < MM; ++j) { lg[j] = logit[i * MM + j]; mx = fmaxf(mx, lg[j]); }
        float ssum = 0.f;
        #pragma unroll
        for (int j = 0; j < MM; ++j) { lg[j] = __expf(lg[j] - mx); ssum += lg[j]; }
        const float inv = 1.0f / ssum;

        float D[4] = {0.f, 0.f, 0.f, 0.f};
        float Wsb[MM][4], Wsp[MM][4];
        #pragma unroll
        for (int j = 0; j < MM; ++j) {
            const float pj = lg[j] * inv;
            const float4 dg = ldq(diag   + j * SIZE + s0);
            const float4 sb = ldq(subpad + j * SIZE + s0);
            const float4 sp = ldq(suppad + j * SIZE + s0);
            D[0] = fmaf(pj, dg.x, D[0]); D[1] = fmaf(pj, dg.y, D[1]);
            D[2] = fmaf(pj, dg.z, D[2]); D[3] = fmaf(pj, dg.w, D[3]);
            Wsb[j][0] = pj * sb.x; Wsb[j][1] = pj * sb.y;
            Wsb[j][2] = pj * sb.z; Wsb[j][3] = pj * sb.w;
            Wsp[j][0] = pj * sp.x; Wsp[j][1] = pj * sp.y;
            Wsp[j][2] = pj * sp.z; Wsp[j][3] = pj * sp.w;
        }

        const bool last = (t == NTERMS - 1);
        for (int r = 0; r < RPB; ++r) {
            const f16* row = &buf[cur][r][0];
            const i2 xo = *(const i2*)&row[s0];
            const i2 xl = *(const i2*)&row[(s0 >= 4)        ? s0 - 4 : 0];
            const i2 xr = *(const i2*)&row[(s0 + 4 <= 1020) ? s0 + 4 : 1020];
            float a0 = 0.f, a1 = 0.f, a2 = 0.f, a3 = 0.f;

            MIX_L(a0, xo.x, D[0]); MIX_H(a1, xo.x, D[1]);
            MIX_L(a2, xo.y, D[2]); MIX_H(a3, xo.y, D[3]);
            MIX_H(a0, xl.y, Wsb[9][0]); MIX_L(a1, xo.x, Wsb[9][1]);
            MIX_H(a2, xo.x, Wsb[9][2]); MIX_L(a3, xo.y, Wsb[9][3]);
            MIX_H(a0, xo.x, Wsp[9][0]); MIX_L(a1, xo.y, Wsp[9][1]);
            MIX_H(a2, xo.y, Wsp[9][2]); MIX_L(a3, xr.x, Wsp[9][3]);
            MIX_L(a0, xl.y, Wsb[8][0]); MIX_H(a1, xl.y, Wsb[8][1]);
            MIX_L(a2, xo.x, Wsb[8][2]); MIX_H(a3, xo.x, Wsb[8][3]);
            MIX_L(a0, xo.y, Wsp[8][0]); MIX_H(a1, xo.y, Wsp[8][1]);
            MIX_L(a2, xr.x, Wsp[8][2]); MIX_H(a3, xr.x, Wsp[8][3]);
            MIX_L(a0, xl.x, Wsb[7][0]); MIX_H(a1, xl.x, Wsb[7][1]);
            MIX_L(a2, xl.y, Wsb[7][2]); MIX_H(a3, xl.y, Wsb[7][3]);
            MIX_L(a0, xr.x, Wsp[7][0]); MIX_H(a1, xr.x, Wsp[7][1]);
            MIX_L(a2, xr.y, Wsp[7][2]); MIX_H(a3, xr.y, Wsp[7][3]);
            #pragma unroll
            for (int j = 0; j <= 6; ++j) {
                const int d = 512 >> j;
                const i2 xm = *(const i2*)&row[(s0 >= d)        ? s0 - d : 0];
                const i2 xp = *(const i2*)&row[(s0 + d <= 1020) ? s0 + d : 1020];
                MIX_L(a0, xm.x, Wsb[j][0]); MIX_H(a1, xm.x, Wsb[j][1]);
                MIX_L(a2, xm.y, Wsb[j][2]); MIX_H(a3, xm.y, Wsb[j][3]);
                MIX_L(a0, xp.x, Wsp[j][0]); MIX_H(a1, xp.x, Wsp[j][1]);
                MIX_L(a2, xp.y, Wsp[j][2]); MIX_H(a3, xp.y, Wsp[j][3]);
            }

            if (last) {
                *(float4*)(out + (rowbase + r) * SIZE + s0) =
                    make_float4(a0, a1, a2, a3);
            } else {
                f16x4 hv;
                hv[0] = (f16)a0; hv[1] = (f16)a1; hv[2] = (f16)a2; hv[3] = (f16)a3;
                *(f16x4*)&buf[cur ^ 1][r][s0] = hv;
            }
        }
        __syncthreads();
        cur ^= 1;
    }
}

extern "C" void kernel_launch(void* const* d_in, const int* in_sizes, int n_in,
                              void* d_out, int out_size, void* d_ws, size_t ws_size,
                              hipStream_t stream) {
    const float* x      = (const float*)d_in[0];
    const float* diag   = (const float*)d_in[1];
    const float* subpad = (const float*)d_in[2];
    const float* suppad = (const float*)d_in[3];
    const float* logit  = (const float*)d_in[4];
    float* outp = (float*)d_out;

    const int batch = in_sizes[0] / SIZE;          // 8192
    const size_t needG  = (size_t)SIZE * SIZE * sizeof(float);  // 4 MB
    const size_t needGt = (size_t)SIZE * SIZE * sizeof(f16);    // 2 MB

    if (d_ws != nullptr && ws_size >= needG + needGt) {
        float* G  = (float*)d_ws;
        f16*   Gt = (f16*)((char*)d_ws + needG);
        precompute_G<<<dim3(SIZE / 2), dim3(256), 0, stream>>>(
            diag, subpad, suppad, logit, G);
        transpose_cast<<<dim3(16, 16), dim3(256), 0, stream>>>(G, Gt);
        const int nblocks = (batch / 128) * (SIZE / 128);       // 512
        gemm_f16<<<dim3(nblocks), dim3(256), 0, stream>>>(x, Gt, outp);
    } else {
        butterfly_h16mix<<<dim3(batch / RPB), dim3(256), 0, stream>>>(
            x, diag, subpad, suppad, logit, outp);
    }
}

// Round 11
// 100.663 us; speedup vs baseline: 1.2553x; 1.2553x over previous
//
#include <hip/hip_runtime.h>

#define SIZE 1024
#define MM 10
#define NTERMS 10

typedef _Float16 f16;
typedef __attribute__((ext_vector_type(8))) _Float16 f16x8;
typedef __attribute__((ext_vector_type(4))) _Float16 f16x4;
typedef __attribute__((ext_vector_type(4))) float    f32x4;
typedef __attribute__((ext_vector_type(2))) int      i2;

__device__ __forceinline__ float4 ldq(const float* p) { return *(const float4*)p; }

#define FMA4F(W, v0, v1, v2, v3)                                     \
    a0 = fmaf((W)[0], (v0), a0); a1 = fmaf((W)[1], (v1), a1);        \
    a2 = fmaf((W)[2], (v2), a2); a3 = fmaf((W)[3], (v3), a3);

// ===========================================================================
// Phase 1: G = A^T (out = x @ G). R7-proven config: 512 blocks x 2 identity
// rows (1024x1 = coef-bound ~27us; 128x8 = latency-bound 63us; 512x2 best).
// ===========================================================================
__global__ __launch_bounds__(256, 2)
void precompute_G(const float* __restrict__ diag,
                  const float* __restrict__ subpad,
                  const float* __restrict__ suppad,
                  const float* __restrict__ logit,
                  float* __restrict__ G)
{
    __shared__ float buf[2][2][SIZE];     // 16 KB

    const int tid = threadIdx.x;
    const int s0  = tid * 4;
    const int rowbase = blockIdx.x * 2;   // 512 blocks x 2 rows = 1024

    #pragma unroll
    for (int r = 0; r < 2; ++r) {
        float4 v;
        v.x = (rowbase + r == s0 + 0) ? 1.f : 0.f;
        v.y = (rowbase + r == s0 + 1) ? 1.f : 0.f;
        v.z = (rowbase + r == s0 + 2) ? 1.f : 0.f;
        v.w = (rowbase + r == s0 + 3) ? 1.f : 0.f;
        *(float4*)&buf[0][r][s0] = v;
    }
    __syncthreads();

    int cur = 0;
    for (int t = 0; t < NTERMS; ++t) {
        const int i = NTERMS - 1 - t;

        float lg[MM];
        float mx = -3.4e38f;
        #pragma unroll
        for (int j = 0; j < MM; ++j) { lg[j] = logit[i * MM + j]; mx = fmaxf(mx, lg[j]); }
        float ssum = 0.f;
        #pragma unroll
        for (int j = 0; j < MM; ++j) { lg[j] = __expf(lg[j] - mx); ssum += lg[j]; }
        const float inv = 1.0f / ssum;

        float D[4] = {0.f, 0.f, 0.f, 0.f};
        float Wsb[MM][4], Wsp[MM][4];
        #pragma unroll
        for (int j = 0; j < MM; ++j) {
            const float pj = lg[j] * inv;
            const float4 dg = ldq(diag   + j * SIZE + s0);
            const float4 sb = ldq(subpad + j * SIZE + s0);
            const float4 sp = ldq(suppad + j * SIZE + s0);
            D[0] = fmaf(pj, dg.x, D[0]); D[1] = fmaf(pj, dg.y, D[1]);
            D[2] = fmaf(pj, dg.z, D[2]); D[3] = fmaf(pj, dg.w, D[3]);
            Wsb[j][0] = pj * sb.x; Wsb[j][1] = pj * sb.y;
            Wsb[j][2] = pj * sb.z; Wsb[j][3] = pj * sb.w;
            Wsp[j][0] = pj * sp.x; Wsp[j][1] = pj * sp.y;
            Wsp[j][2] = pj * sp.z; Wsp[j][3] = pj * sp.w;
        }

        const bool last = (t == NTERMS - 1);
        for (int r = 0; r < 2; ++r) {
            const float* row = &buf[cur][r][0];

            const float4 xo = ldq(row + s0);
            float a0 = D[0] * xo.x, a1 = D[1] * xo.y,
                  a2 = D[2] * xo.z, a3 = D[3] * xo.w;

            const float4 xl = ldq(row + (s0 >= 4         ? s0 - 4 : 0));
            const float4 xr = ldq(row + (s0 + 4 <= 1020  ? s0 + 4 : 1020));

            FMA4F(Wsb[9], xl.w, xo.x, xo.y, xo.z)
            FMA4F(Wsp[9], xo.y, xo.z, xo.w, xr.x)
            FMA4F(Wsb[8], xl.z, xl.w, xo.x, xo.y)
            FMA4F(Wsp[8], xo.z, xo.w, xr.x, xr.y)
            FMA4F(Wsb[7], xl.x, xl.y, xl.z, xl.w)
            FMA4F(Wsp[7], xr.x, xr.y, xr.z, xr.w)
            #pragma unroll
            for (int j = 0; j <= 6; ++j) {
                const int d = 512 >> j;
                const float4 xm = ldq(row + (s0 >= d        ? s0 - d : 0));
                const float4 xp = ldq(row + (s0 + d <= 1020 ? s0 + d : 1020));
                FMA4F(Wsb[j], xm.x, xm.y, xm.z, xm.w)
                FMA4F(Wsp[j], xp.x, xp.y, xp.z, xp.w)
            }

            if (last) {
                *(float4*)(G + (long)(rowbase + r) * SIZE + s0) =
                    make_float4(a0, a1, a2, a3);
            } else {
                *(float4*)&buf[cur ^ 1][r][s0] = make_float4(a0, a1, a2, a3);
            }
        }
        __syncthreads();
        cur ^= 1;
    }
}

// ===========================================================================
// Phase 2: Gt[s][k] = (f16) G[k][s]
// ===========================================================================
__global__ __launch_bounds__(256)
void transpose_cast(const float* __restrict__ G, f16* __restrict__ Gt)
{
    __shared__ float tile[64][65];
    const int tid = threadIdx.x;
    const int k0 = blockIdx.x * 64;
    const int s0 = blockIdx.y * 64;
    const int rr = tid >> 4;
    const int cc = (tid & 15) * 4;

    #pragma unroll
    for (int p = 0; p < 4; ++p) {
        const float4 v = ldq(G + (long)(k0 + rr + p * 16) * SIZE + s0 + cc);
        *(float4*)&tile[rr + p * 16][cc] = v;
    }
    __syncthreads();
    #pragma unroll
    for (int p = 0; p < 4; ++p) {
        const int s = rr + p * 16;
        f16x4 h;
        h[0] = (f16)tile[cc + 0][s];
        h[1] = (f16)tile[cc + 1][s];
        h[2] = (f16)tile[cc + 2][s];
        h[3] = (f16)tile[cc + 3][s];
        *(f16x4*)(Gt + (long)(s0 + s) * SIZE + k0 + cc) = h;
    }
}

// ===========================================================================
// Phase 3 (R11): R9's PROVEN LDS/barrier GEMM (58us) with ONE knob: BN 128->64
// -> grid 512->1024 blocks = 4 blocks/CU, 16 waves/CU. R10 proved plain-HIP
// register pipelines get destroyed by the allocator (VGPR 84, loads sunk,
// 97us); R9 proved the barrier version is latency-bound at 2 blocks/CU.
// Doubling the independent barrier-groups per CU is the remaining
// structure-preserving lever. A-staging code is byte-identical to R9.
// Wave tile 64x32: acc[4][2], 8 MFMA + 2 B-loads per kt.
// ===========================================================================
#define BMT 128
#define BNT 64
#define BKT 32
#define PADK 36
#define NKT (1024 / BKT)

__device__ __forceinline__ void cvt16(const float4& v0, const float4& v1, f16x8& h) {
    h[0] = (f16)v0.x; h[1] = (f16)v0.y; h[2] = (f16)v0.z; h[3] = (f16)v0.w;
    h[4] = (f16)v1.x; h[5] = (f16)v1.y; h[6] = (f16)v1.z; h[7] = (f16)v1.w;
}

__global__ __launch_bounds__(256, 2)
void gemm_f16(const float* __restrict__ x,
              const f16* __restrict__ Gt,
              float* __restrict__ out)
{
    __shared__ f16 Xs[2][BMT][PADK];   // 18 KB

    const int tid  = threadIdx.x;
    const int bm   = blockIdx.x & 63;          // same-bm -> same XCD (64%8==0)
    const int bn   = blockIdx.x >> 6;          // 0..15
    const int w    = tid >> 6, lane = tid & 63;
    const int wm   = w >> 1,  wn   = w & 1;
    const int lr   = lane & 15, lk = lane >> 4;

    const int sr = tid >> 1;
    const int sk = (tid & 1) * 16;
    const float* xrow = x + (long)(bm * BMT + sr) * 1024 + sk;

    // B frag rows: n = bn*64 + wn*32 + ni*16 + lr, k = lk*8 (+kt*32)
    const f16* gbase = Gt + (long)(bn * BNT + wn * 32 + lr) * 1024 + lk * 8;

    f32x4 acc[4][2];
    #pragma unroll
    for (int mi = 0; mi < 4; ++mi)
        #pragma unroll
        for (int ni = 0; ni < 2; ++ni)
            acc[mi][ni] = (f32x4){0.f, 0.f, 0.f, 0.f};

    float4 v0, v1, v2, v3;             // A stage regs
    f16x8 b0, b1;                      // B frags (even kt)
    f16x8 c0, c1;                      // B frags (odd kt)

#define LOAD_A(KT) {                                                  \
        const float* xp = xrow + (KT) * BKT;                          \
        v0 = ldq(xp); v1 = ldq(xp + 4);                               \
        v2 = ldq(xp + 8); v3 = ldq(xp + 12); }
#define WRITE_A(BUF) {                                                \
        f16x8 h0, h1; cvt16(v0, v1, h0); cvt16(v2, v3, h1);           \
        *(f16x8*)&Xs[BUF][sr][sk]     = h0;                           \
        *(f16x8*)&Xs[BUF][sr][sk + 8] = h1; }
#define LOAD_B(B0, B1, KT) {                                          \
        const f16* gp = gbase + (KT) * BKT;                           \
        B0 = *(const f16x8*)(gp);                                     \
        B1 = *(const f16x8*)(gp + 16 * 1024); }
#define COMPUTE(BUF, B0, B1) {                                        \
        f16x8 a0 = *(const f16x8*)&Xs[BUF][wm * 64 +  0 + lr][lk * 8];\
        f16x8 a1 = *(const f16x8*)&Xs[BUF][wm * 64 + 16 + lr][lk * 8];\
        f16x8 a2 = *(const f16x8*)&Xs[BUF][wm * 64 + 32 + lr][lk * 8];\
        f16x8 a3 = *(const f16x8*)&Xs[BUF][wm * 64 + 48 + lr][lk * 8];\
        acc[0][0] = __builtin_amdgcn_mfma_f32_16x16x32_f16(a0, B0, acc[0][0], 0, 0, 0); \
        acc[0][1] = __builtin_amdgcn_mfma_f32_16x16x32_f16(a0, B1, acc[0][1], 0, 0, 0); \
        acc[1][0] = __builtin_amdgcn_mfma_f32_16x16x32_f16(a1, B0, acc[1][0], 0, 0, 0); \
        acc[1][1] = __builtin_amdgcn_mfma_f32_16x16x32_f16(a1, B1, acc[1][1], 0, 0, 0); \
        acc[2][0] = __builtin_amdgcn_mfma_f32_16x16x32_f16(a2, B0, acc[2][0], 0, 0, 0); \
        acc[2][1] = __builtin_amdgcn_mfma_f32_16x16x32_f16(a2, B1, acc[2][1], 0, 0, 0); \
        acc[3][0] = __builtin_amdgcn_mfma_f32_16x16x32_f16(a3, B0, acc[3][0], 0, 0, 0); \
        acc[3][1] = __builtin_amdgcn_mfma_f32_16x16x32_f16(a3, B1, acc[3][1], 0, 0, 0); }

    LOAD_A(0); WRITE_A(0); LOAD_B(b0, b1, 0);
    __syncthreads();

    #pragma unroll 1
    for (int kt2 = 0; kt2 < NKT / 2; ++kt2) {
        const int kt = kt2 * 2;
        LOAD_A(kt + 1);
        LOAD_B(c0, c1, kt + 1);
        COMPUTE(0, b0, b1);
        WRITE_A(1);
        __syncthreads();
        if (kt2 < NKT / 2 - 1) {
            LOAD_A(kt + 2);
            LOAD_B(b0, b1, kt + 2);
        }
        COMPUTE(1, c0, c1);
        if (kt2 < NKT / 2 - 1) {
            WRITE_A(0);
        }
        __syncthreads();
    }

    // epilogue: D lane l,q -> row (l>>4)*4+q, col l&15   (R7-verified)
    const long orow0 = (long)bm * BMT + wm * 64 + lk * 4;
    const int  ocol0 = bn * BNT + wn * 32 + lr;
    #pragma unroll
    for (int mi = 0; mi < 4; ++mi)
        #pragma unroll
        for (int ni = 0; ni < 2; ++ni)
            #pragma unroll
            for (int q = 0; q < 4; ++q)
                out[(orow0 + mi * 16 + q) * 1024 + ocol0 + ni * 16] = acc[mi][ni][q];

#undef LOAD_A
#undef WRITE_A
#undef LOAD_B
#undef COMPUTE
}

// ===========================================================================
// Fallback (ws too small): R6's proven stencil kernel.
// ===========================================================================
#define RPB 16
#define MIX_L(acc, r32, ww) \
    asm("v_fma_mix_f32 %0, %1, %2, %0 op_sel:[0,0,0] op_sel_hi:[1,0,0]" \
        : "+v"(acc) : "v"(r32), "v"(ww))
#define MIX_H(acc, r32, ww) \
    asm("v_fma_mix_f32 %0, %1, %2, %0 op_sel:[1,0,0] op_sel_hi:[1,0,0]" \
        : "+v"(acc) : "v"(r32), "v"(ww))

__global__ __launch_bounds__(256, 2)
void butterfly_h16mix(const float* __restrict__ x,
                      const float* __restrict__ diag,
                      const float* __restrict__ subpad,
                      const float* __restrict__ suppad,
                      const float* __restrict__ logit,
                      float* __restrict__ out)
{
    __shared__ f16 buf[2][RPB][SIZE];
    const int tid = threadIdx.x;
    const int s0  = tid * 4;
    const long rowbase = (long)blockIdx.x * RPB;

    #pragma unroll
    for (int r = 0; r < RPB; ++r) {
        const float4 v = ldq(x + (rowbase + r) * SIZE + s0);
        f16x4 h;
        h[0] = (f16)v.x; h[1] = (f16)v.y; h[2] = (f16)v.z; h[3] = (f16)v.w;
        *(f16x4*)&buf[0][r][s0] = h;
    }
    __syncthreads();

    int cur = 0;
    for (int t = 0; t < NTERMS; ++t) {
        const int i = NTERMS - 1 - t;
        float lg[MM];
        float mx = -3.4e38f;
        #pragma unroll
        for (int j = 0; j < MM; ++j) { lg[j] = logit[i * MM + j]; mx = fmaxf(mx, lg[j]); }
        float ssum = 0.f;
        #pragma unroll
        for (int j = 0; j < MM; ++j) { lg[j] = __expf(lg[j] - mx); ssum += lg[j]; }
        const float inv = 1.0f / ssum;

        float D[4] = {0.f, 0.f, 0.f, 0.f};
        float Wsb[MM][4], Wsp[MM][4];
        #pragma unroll
        for (int j = 0; j < MM; ++j) {
            const float pj = lg[j] * inv;
            const float4 dg = ldq(diag   + j * SIZE + s0);
            const float4 sb = ldq(subpad + j * SIZE + s0);
            const float4 sp = ldq(suppad + j * SIZE + s0);
            D[0] = fmaf(pj, dg.x, D[0]); D[1] = fmaf(pj, dg.y, D[1]);
            D[2] = fmaf(pj, dg.z, D[2]); D[3] = fmaf(pj, dg.w, D[3]);
            Wsb[j][0] = pj * sb.x; Wsb[j][1] = pj * sb.y;
            Wsb[j][2] = pj * sb.z; Wsb[j][3] = pj * sb.w;
            Wsp[j][0] = pj * sp.x; Wsp[j][1] = pj * sp.y;
            Wsp[j][2] = pj * sp.z; Wsp[j][3] = pj * sp.w;
        }

        const bool last = (t == NTERMS - 1);
        for (int r = 0; r < RPB; ++r) {
            const f16* row = &buf[cur][r][0];
            const i2 xo = *(const i2*)&row[s0];
            const i2 xl = *(const i2*)&row[(s0 >= 4)        ? s0 - 4 : 0];
            const i2 xr = *(const i2*)&row[(s0 + 4 <= 1020) ? s0 + 4 : 1020];
            float a0 = 0.f, a1 = 0.f, a2 = 0.f, a3 = 0.f;

            MIX_L(a0, xo.x, D[0]); MIX_H(a1, xo.x, D[1]);
            MIX_L(a2, xo.y, D[2]); MIX_H(a3, xo.y, D[3]);
            MIX_H(a0, xl.y, Wsb[9][0]); MIX_L(a1, xo.x, Wsb[9][1]);
            MIX_H(a2, xo.x, Wsb[9][2]); MIX_L(a3, xo.y, Wsb[9][3]);
            MIX_H(a0, xo.x, Wsp[9][0]); MIX_L(a1, xo.y, Wsp[9][1]);
            MIX_H(a2, xo.y, Wsp[9][2]); MIX_L(a3, xr.x, Wsp[9][3]);
            MIX_L(a0, xl.y, Wsb[8][0]); MIX_H(a1, xl.y, Wsb[8][1]);
            MIX_L(a2, xo.x, Wsb[8][2]); MIX_H(a3, xo.x, Wsb[8][3]);
            MIX_L(a0, xo.y, Wsp[8][0]); MIX_H(a1, xo.y, Wsp[8][1]);
            MIX_L(a2, xr.x, Wsp[8][2]); MIX_H(a3, xr.x, Wsp[8][3]);
            MIX_L(a0, xl.x, Wsb[7][0]); MIX_H(a1, xl.x, Wsb[7][1]);
            MIX_L(a2, xl.y, Wsb[7][2]); MIX_H(a3, xl.y, Wsb[7][3]);
            MIX_L(a0, xr.x, Wsp[7][0]); MIX_H(a1, xr.x, Wsp[7][1]);
            MIX_L(a2, xr.y, Wsp[7][2]); MIX_H(a3, xr.y, Wsp[7][3]);
            #pragma unroll
            for (int j = 0; j <= 6; ++j) {
                const int d = 512 >> j;
                const i2 xm = *(const i2*)&row[(s0 >= d)        ? s0 - d : 0];
                const i2 xp = *(const i2*)&row[(s0 + d <= 1020) ? s0 + d : 1020];
                MIX_L(a0, xm.x, Wsb[j][0]); MIX_H(a1, xm.x, Wsb[j][1]);
                MIX_L(a2, xm.y, Wsb[j][2]); MIX_H(a3, xm.y, Wsb[j][3]);
                MIX_L(a0, xp.x, Wsp[j][0]); MIX_H(a1, xp.x, Wsp[j][1]);
                MIX_L(a2, xp.y, Wsp[j][2]); MIX_H(a3, xp.y, Wsp[j][3]);
            }

            if (last) {
                *(float4*)(out + (rowbase + r) * SIZE + s0) =
                    make_float4(a0, a1, a2, a3);
            } else {
                f16x4 hv;
                hv[0] = (f16)a0; hv[1] = (f16)a1; hv[2] = (f16)a2; hv[3] = (f16)a3;
                *(f16x4*)&buf[cur ^ 1][r][s0] = hv;
            }
        }
        __syncthreads();
        cur ^= 1;
    }
}

extern "C" void kernel_launch(void* const* d_in, const int* in_sizes, int n_in,
                              void* d_out, int out_size, void* d_ws, size_t ws_size,
                              hipStream_t stream) {
    const float* x      = (const float*)d_in[0];
    const float* diag   = (const float*)d_in[1];
    const float* subpad = (const float*)d_in[2];
    const float* suppad = (const float*)d_in[3];
    const float* logit  = (const float*)d_in[4];
    float* outp = (float*)d_out;

    const int batch = in_sizes[0] / SIZE;          // 8192
    const size_t needG  = (size_t)SIZE * SIZE * sizeof(float);  // 4 MB
    const size_t needGt = (size_t)SIZE * SIZE * sizeof(f16);    // 2 MB

    if (d_ws != nullptr && ws_size >= needG + needGt) {
        float* G  = (float*)d_ws;
        f16*   Gt = (f16*)((char*)d_ws + needG);
        precompute_G<<<dim3(SIZE / 2), dim3(256), 0, stream>>>(
            diag, subpad, suppad, logit, G);
        transpose_cast<<<dim3(16, 16), dim3(256), 0, stream>>>(G, Gt);
        const int nblocks = (batch / BMT) * (SIZE / BNT);       // 64*16 = 1024
        gemm_f16<<<dim3(nblocks), dim3(256), 0, stream>>>(x, Gt, outp);
    } else {
        butterfly_h16mix<<<dim3(batch / RPB), dim3(256), 0, stream>>>(
            x, diag, subpad, suppad, logit, outp);
    }
}

// Round 12
// 87.391 us; speedup vs baseline: 1.4460x; 1.1519x over previous
//
#include <hip/hip_runtime.h>

#define SIZE 1024
#define MM 10
#define NTERMS 10

typedef _Float16 f16;
typedef __attribute__((ext_vector_type(8))) _Float16 f16x8;
typedef __attribute__((ext_vector_type(4))) _Float16 f16x4;
typedef __attribute__((ext_vector_type(4))) float    f32x4;
typedef __attribute__((ext_vector_type(2))) int      i2;

typedef const __attribute__((address_space(1))) _Float16 gf16;  // global
typedef __attribute__((address_space(3))) _Float16 sf16;        // LDS

__device__ __forceinline__ float4 ldq(const float* p) { return *(const float4*)p; }

#define FMA4F(W, v0, v1, v2, v3)                                     \
    a0 = fmaf((W)[0], (v0), a0); a1 = fmaf((W)[1], (v1), a1);        \
    a2 = fmaf((W)[2], (v2), a2); a3 = fmaf((W)[3], (v3), a3);

__device__ __forceinline__ void cvt16(const float4& v0, const float4& v1, f16x8& h) {
    h[0] = (f16)v0.x; h[1] = (f16)v0.y; h[2] = (f16)v0.z; h[3] = (f16)v0.w;
    h[4] = (f16)v1.x; h[5] = (f16)v1.y; h[6] = (f16)v1.z; h[7] = (f16)v1.w;
}

// ===========================================================================
// Phase 0: xh = (f16) x   — one-time RTN cast (same cvt the gemm did 8x).
// 48MB traffic ~8us. Enables global_load_lds A-staging (f16 src, no cvt).
// ===========================================================================
__global__ __launch_bounds__(256)
void cvt_x(const float* __restrict__ x, f16* __restrict__ xh)
{
    const long i = ((long)blockIdx.x * 256 + threadIdx.x) * 16;
    const float4 a = ldq(x + i), b = ldq(x + i + 4),
                 c = ldq(x + i + 8), d = ldq(x + i + 12);
    f16x8 h0, h1; cvt16(a, b, h0); cvt16(c, d, h1);
    *(f16x8*)(xh + i)     = h0;
    *(f16x8*)(xh + i + 8) = h1;
}

// ===========================================================================
// Phase 1: G = A^T (out = x @ G). R7-proven config: 512 blocks x 2 identity
// rows (1024x1 coef-bound; 128x8 latency-bound; 512x2 measured best, ~15us).
// ===========================================================================
__global__ __launch_bounds__(256, 2)
void precompute_G(const float* __restrict__ diag,
                  const float* __restrict__ subpad,
                  const float* __restrict__ suppad,
                  const float* __restrict__ logit,
                  float* __restrict__ G)
{
    __shared__ float buf[2][2][SIZE];     // 16 KB

    const int tid = threadIdx.x;
    const int s0  = tid * 4;
    const int rowbase = blockIdx.x * 2;   // 512 blocks x 2 rows = 1024

    #pragma unroll
    for (int r = 0; r < 2; ++r) {
        float4 v;
        v.x = (rowbase + r == s0 + 0) ? 1.f : 0.f;
        v.y = (rowbase + r == s0 + 1) ? 1.f : 0.f;
        v.z = (rowbase + r == s0 + 2) ? 1.f : 0.f;
        v.w = (rowbase + r == s0 + 3) ? 1.f : 0.f;
        *(float4*)&buf[0][r][s0] = v;
    }
    __syncthreads();

    int cur = 0;
    for (int t = 0; t < NTERMS; ++t) {
        const int i = NTERMS - 1 - t;

        float lg[MM];
        float mx = -3.4e38f;
        #pragma unroll
        for (int j = 0; j < MM; ++j) { lg[j] = logit[i * MM + j]; mx = fmaxf(mx, lg[j]); }
        float ssum = 0.f;
        #pragma unroll
        for (int j = 0; j < MM; ++j) { lg[j] = __expf(lg[j] - mx); ssum += lg[j]; }
        const float inv = 1.0f / ssum;

        float D[4] = {0.f, 0.f, 0.f, 0.f};
        float Wsb[MM][4], Wsp[MM][4];
        #pragma unroll
        for (int j = 0; j < MM; ++j) {
            const float pj = lg[j] * inv;
            const float4 dg = ldq(diag   + j * SIZE + s0);
            const float4 sb = ldq(subpad + j * SIZE + s0);
            const float4 sp = ldq(suppad + j * SIZE + s0);
            D[0] = fmaf(pj, dg.x, D[0]); D[1] = fmaf(pj, dg.y, D[1]);
            D[2] = fmaf(pj, dg.z, D[2]); D[3] = fmaf(pj, dg.w, D[3]);
            Wsb[j][0] = pj * sb.x; Wsb[j][1] = pj * sb.y;
            Wsb[j][2] = pj * sb.z; Wsb[j][3] = pj * sb.w;
            Wsp[j][0] = pj * sp.x; Wsp[j][1] = pj * sp.y;
            Wsp[j][2] = pj * sp.z; Wsp[j][3] = pj * sp.w;
        }

        const bool last = (t == NTERMS - 1);
        for (int r = 0; r < 2; ++r) {
            const float* row = &buf[cur][r][0];

            const float4 xo = ldq(row + s0);
            float a0 = D[0] * xo.x, a1 = D[1] * xo.y,
                  a2 = D[2] * xo.z, a3 = D[3] * xo.w;

            const float4 xl = ldq(row + (s0 >= 4         ? s0 - 4 : 0));
            const float4 xr = ldq(row + (s0 + 4 <= 1020  ? s0 + 4 : 1020));

            FMA4F(Wsb[9], xl.w, xo.x, xo.y, xo.z)
            FMA4F(Wsp[9], xo.y, xo.z, xo.w, xr.x)
            FMA4F(Wsb[8], xl.z, xl.w, xo.x, xo.y)
            FMA4F(Wsp[8], xo.z, xo.w, xr.x, xr.y)
            FMA4F(Wsb[7], xl.x, xl.y, xl.z, xl.w)
            FMA4F(Wsp[7], xr.x, xr.y, xr.z, xr.w)
            #pragma unroll
            for (int j = 0; j <= 6; ++j) {
                const int d = 512 >> j;
                const float4 xm = ldq(row + (s0 >= d        ? s0 - d : 0));
                const float4 xp = ldq(row + (s0 + d <= 1020 ? s0 + d : 1020));
                FMA4F(Wsb[j], xm.x, xm.y, xm.z, xm.w)
                FMA4F(Wsp[j], xp.x, xp.y, xp.z, xp.w)
            }

            if (last) {
                *(float4*)(G + (long)(rowbase + r) * SIZE + s0) =
                    make_float4(a0, a1, a2, a3);
            } else {
                *(float4*)&buf[cur ^ 1][r][s0] = make_float4(a0, a1, a2, a3);
            }
        }
        __syncthreads();
        cur ^= 1;
    }
}

// ===========================================================================
// Phase 2: Gt[s][k] = (f16) G[k][s]
// ===========================================================================
__global__ __launch_bounds__(256)
void transpose_cast(const float* __restrict__ G, f16* __restrict__ Gt)
{
    __shared__ float tile[64][65];
    const int tid = threadIdx.x;
    const int k0 = blockIdx.x * 64;
    const int s0 = blockIdx.y * 64;
    const int rr = tid >> 4;
    const int cc = (tid & 15) * 4;

    #pragma unroll
    for (int p = 0; p < 4; ++p) {
        const float4 v = ldq(G + (long)(k0 + rr + p * 16) * SIZE + s0 + cc);
        *(float4*)&tile[rr + p * 16][cc] = v;
    }
    __syncthreads();
    #pragma unroll
    for (int p = 0; p < 4; ++p) {
        const int s = rr + p * 16;
        f16x4 h;
        h[0] = (f16)tile[cc + 0][s];
        h[1] = (f16)tile[cc + 1][s];
        h[2] = (f16)tile[cc + 2][s];
        h[3] = (f16)tile[cc + 3][s];
        *(f16x4*)(Gt + (long)(s0 + s) * SIZE + k0 + cc) = h;
    }
}

// ===========================================================================
// Phase 3 (R12): R9's proven GEMM (58us, BN=128, B-from-global regs,
// bm-XCD-swizzle) with A-staging swapped to global_load_lds width=16
// (the compiler never auto-emits it — m97 ladder's biggest lever, +67%):
//  * A src = pre-cast xh (f16) -> no fp32 regs, no cvt VALU, no ds_write
//    in the loop; staging is fire-and-forget DMA (nothing for the
//    allocator to sink — R10/R11's failure mode structurally removed).
//  * Xs is LINEAR [128][32] f16 (gload_lds needs linear dest). Frag reads
//    at row*64B + lk*16B are bank-UNIFORM (8 lanes per 4-bank group = the
//    b128 floor) -> padding unnecessary.
//  * dest byte for thread t = t*16 -> row=t>>2, 16B-slot=t&3; wave-uniform
//    LDS base = wave*1024B, issue1 at +4096B (rows 64..127).
// Same MFMA order/values as R9 -> absmax exactly 0.0625.
// ===========================================================================
#define BMT 128
#define BNT 128
#define BKT 32
#define NKT (1024 / BKT)

__global__ __launch_bounds__(256, 2)
void gemm_f16(const f16* __restrict__ xh,
              const f16* __restrict__ Gt,
              float* __restrict__ out)
{
    __shared__ f16 Xs[2][BMT][BKT];    // 16 KB, linear

    const int tid  = threadIdx.x;
    const int bm   = blockIdx.x & 63;          // same-bm -> same XCD (64%8==0)
    const int bn   = blockIdx.x >> 6;          // 0..7
    const int w    = tid >> 6, lane = tid & 63;
    const int wm   = w >> 1,  wn   = w & 1;
    const int lr   = lane & 15, lk = lane >> 4;

    // A staging source: thread t -> row t>>2 (+64 for issue 1), 16B-slot t&3
    const f16* gsrc = xh + (long)(bm * BMT + (tid >> 2)) * 1024 + (tid & 3) * 8;

    // B frag rows: n = bn*128 + wn*64 + ni*16 + lr, k = lk*8 (+kt*32)
    const f16* gbase = Gt + (long)(bn * BNT + wn * 64 + lr) * 1024 + lk * 8;

    f32x4 acc[4][4];
    #pragma unroll
    for (int mi = 0; mi < 4; ++mi)
        #pragma unroll
        for (int ni = 0; ni < 4; ++ni)
            acc[mi][ni] = (f32x4){0.f, 0.f, 0.f, 0.f};

    f16x8 b0, b1, b2, b3;              // B frags (even kt)
    f16x8 c0, c1, c2, c3;              // B frags (odd kt)

#define STAGE(BUF, KT) {                                                      \
        const f16* gp = gsrc + (KT) * BKT;                                    \
        sf16* lp = (sf16*)(&Xs[BUF][0][0] + (tid >> 6) * 512);                \
        __builtin_amdgcn_global_load_lds((gf16*)gp,              lp,       16, 0, 0); \
        __builtin_amdgcn_global_load_lds((gf16*)(gp + 64 * 1024), lp + 2048, 16, 0, 0); }
#define LOAD_B(B0, B1, B2, B3, KT) {                                  \
        const f16* gp = gbase + (KT) * BKT;                           \
        B0 = *(const f16x8*)(gp);                                     \
        B1 = *(const f16x8*)(gp + 16 * 1024);                         \
        B2 = *(const f16x8*)(gp + 32 * 1024);                         \
        B3 = *(const f16x8*)(gp + 48 * 1024); }
#define COMPUTE(BUF, B0, B1, B2, B3) {                                \
        f16x8 a0 = *(const f16x8*)&Xs[BUF][wm * 64 +  0 + lr][lk * 8];\
        f16x8 a1 = *(const f16x8*)&Xs[BUF][wm * 64 + 16 + lr][lk * 8];\
        f16x8 a2 = *(const f16x8*)&Xs[BUF][wm * 64 + 32 + lr][lk * 8];\
        f16x8 a3 = *(const f16x8*)&Xs[BUF][wm * 64 + 48 + lr][lk * 8];\
        acc[0][0] = __builtin_amdgcn_mfma_f32_16x16x32_f16(a0, B0, acc[0][0], 0, 0, 0); \
        acc[0][1] = __builtin_amdgcn_mfma_f32_16x16x32_f16(a0, B1, acc[0][1], 0, 0, 0); \
        acc[0][2] = __builtin_amdgcn_mfma_f32_16x16x32_f16(a0, B2, acc[0][2], 0, 0, 0); \
        acc[0][3] = __builtin_amdgcn_mfma_f32_16x16x32_f16(a0, B3, acc[0][3], 0, 0, 0); \
        acc[1][0] = __builtin_amdgcn_mfma_f32_16x16x32_f16(a1, B0, acc[1][0], 0, 0, 0); \
        acc[1][1] = __builtin_amdgcn_mfma_f32_16x16x32_f16(a1, B1, acc[1][1], 0, 0, 0); \
        acc[1][2] = __builtin_amdgcn_mfma_f32_16x16x32_f16(a1, B2, acc[1][2], 0, 0, 0); \
        acc[1][3] = __builtin_amdgcn_mfma_f32_16x16x32_f16(a1, B3, acc[1][3], 0, 0, 0); \
        acc[2][0] = __builtin_amdgcn_mfma_f32_16x16x32_f16(a2, B0, acc[2][0], 0, 0, 0); \
        acc[2][1] = __builtin_amdgcn_mfma_f32_16x16x32_f16(a2, B1, acc[2][1], 0, 0, 0); \
        acc[2][2] = __builtin_amdgcn_mfma_f32_16x16x32_f16(a2, B2, acc[2][2], 0, 0, 0); \
        acc[2][3] = __builtin_amdgcn_mfma_f32_16x16x32_f16(a2, B3, acc[2][3], 0, 0, 0); \
        acc[3][0] = __builtin_amdgcn_mfma_f32_16x16x32_f16(a3, B0, acc[3][0], 0, 0, 0); \
        acc[3][1] = __builtin_amdgcn_mfma_f32_16x16x32_f16(a3, B1, acc[3][1], 0, 0, 0); \
        acc[3][2] = __builtin_amdgcn_mfma_f32_16x16x32_f16(a3, B2, acc[3][2], 0, 0, 0); \
        acc[3][3] = __builtin_amdgcn_mfma_f32_16x16x32_f16(a3, B3, acc[3][3], 0, 0, 0); }

    // prologue: stage kt 0 into buf0, B(0) -> regs
    STAGE(0, 0); LOAD_B(b0, b1, b2, b3, 0);
    __syncthreads();

    #pragma unroll 1
    for (int kt2 = 0; kt2 < NKT / 2; ++kt2) {
        const int kt = kt2 * 2;
        STAGE(1, kt + 1);                      // DMA next tile (in flight)
        LOAD_B(c0, c1, c2, c3, kt + 1);
        COMPUTE(0, b0, b1, b2, b3);
        __syncthreads();                       // drains DMA -> buf1 ready
        if (kt2 < NKT / 2 - 1) {
            STAGE(0, kt + 2);
            LOAD_B(b0, b1, b2, b3, kt + 2);
        }
        COMPUTE(1, c0, c1, c2, c3);
        __syncthreads();
    }

    // epilogue: D lane l,q -> row (l>>4)*4+q, col l&15   (R7-verified)
    const long orow0 = (long)bm * BMT + wm * 64 + lk * 4;
    const int  ocol0 = bn * BNT + wn * 64 + lr;
    #pragma unroll
    for (int mi = 0; mi < 4; ++mi)
        #pragma unroll
        for (int ni = 0; ni < 4; ++ni)
            #pragma unroll
            for (int q = 0; q < 4; ++q)
                out[(orow0 + mi * 16 + q) * 1024 + ocol0 + ni * 16] = acc[mi][ni][q];

#undef STAGE
#undef LOAD_B
#undef COMPUTE
}

// ===========================================================================
// Fallback (ws too small): R6's proven stencil kernel.
// ===========================================================================
#define RPB 16
#define MIX_L(acc, r32, ww) \
    asm("v_fma_mix_f32 %0, %1, %2, %0 op_sel:[0,0,0] op_sel_hi:[1,0,0]" \
        : "+v"(acc) : "v"(r32), "v"(ww))
#define MIX_H(acc, r32, ww) \
    asm("v_fma_mix_f32 %0, %1, %2, %0 op_sel:[1,0,0] op_sel_hi:[1,0,0]" \
        : "+v"(acc) : "v"(r32), "v"(ww))

__global__ __launch_bounds__(256, 2)
void butterfly_h16mix(const float* __restrict__ x,
                      const float* __restrict__ diag,
                      const float* __restrict__ subpad,
                      const float* __restrict__ suppad,
                      const float* __restrict__ logit,
                      float* __restrict__ out)
{
    __shared__ f16 buf[2][RPB][SIZE];
    const int tid = threadIdx.x;
    const int s0  = tid * 4;
    const long rowbase = (long)blockIdx.x * RPB;

    #pragma unroll
    for (int r = 0; r < RPB; ++r) {
        const float4 v = ldq(x + (rowbase + r) * SIZE + s0);
        f16x4 h;
        h[0] = (f16)v.x; h[1] = (f16)v.y; h[2] = (f16)v.z; h[3] = (f16)v.w;
        *(f16x4*)&buf[0][r][s0] = h;
    }
    __syncthreads();

    int cur = 0;
    for (int t = 0; t < NTERMS; ++t) {
        const int i = NTERMS - 1 - t;
        float lg[MM];
        float mx = -3.4e38f;
        #pragma unroll
        for (int j = 0; j < MM; ++j) { lg[j] = logit[i * MM + j]; mx = fmaxf(mx, lg[j]); }
        float ssum = 0.f;
        #pragma unroll
        for (int j = 0; j < MM; ++j) { lg[j] = __expf(lg[j] - mx); ssum += lg[j]; }
        const float inv = 1.0f / ssum;

        float D[4] = {0.f, 0.f, 0.f, 0.f};
        float Wsb[MM][4], Wsp[MM][4];
        #pragma unroll
        for (int j = 0; j < MM; ++j) {
            const float pj = lg[j] * inv;
            const float4 dg = ldq(diag   + j * SIZE + s0);
            const float4 sb = ldq(subpad + j * SIZE + s0);
            const float4 sp = ldq(suppad + j * SIZE + s0);
            D[0] = fmaf(pj, dg.x, D[0]); D[1] = fmaf(pj, dg.y, D[1]);
            D[2] = fmaf(pj, dg.z, D[2]); D[3] = fmaf(pj, dg.w, D[3]);
            Wsb[j][0] = pj * sb.x; Wsb[j][1] = pj * sb.y;
            Wsb[j][2] = pj * sb.z; Wsb[j][3] = pj * sb.w;
            Wsp[j][0] = pj * sp.x; Wsp[j][1] = pj * sp.y;
            Wsp[j][2] = pj * sp.z; Wsp[j][3] = pj * sp.w;
        }

        const bool last = (t == NTERMS - 1);
        for (int r = 0; r < RPB; ++r) {
            const f16* row = &buf[cur][r][0];
            const i2 xo = *(const i2*)&row[s0];
            const i2 xl = *(const i2*)&row[(s0 >= 4)        ? s0 - 4 : 0];
            const i2 xr = *(const i2*)&row[(s0 + 4 <= 1020) ? s0 + 4 : 1020];
            float a0 = 0.f, a1 = 0.f, a2 = 0.f, a3 = 0.f;

            MIX_L(a0, xo.x, D[0]); MIX_H(a1, xo.x, D[1]);
            MIX_L(a2, xo.y, D[2]); MIX_H(a3, xo.y, D[3]);
            MIX_H(a0, xl.y, Wsb[9][0]); MIX_L(a1, xo.x, Wsb[9][1]);
            MIX_H(a2, xo.x, Wsb[9][2]); MIX_L(a3, xo.y, Wsb[9][3]);
            MIX_H(a0, xo.x, Wsp[9][0]); MIX_L(a1, xo.y, Wsp[9][1]);
            MIX_H(a2, xo.y, Wsp[9][2]); MIX_L(a3, xr.x, Wsp[9][3]);
            MIX_L(a0, xl.y, Wsb[8][0]); MIX_H(a1, xl.y, Wsb[8][1]);
            MIX_L(a2, xo.x, Wsb[8][2]); MIX_H(a3, xo.x, Wsb[8][3]);
            MIX_L(a0, xo.y, Wsp[8][0]); MIX_H(a1, xo.y, Wsp[8][1]);
            MIX_L(a2, xr.x, Wsp[8][2]); MIX_H(a3, xr.x, Wsp[8][3]);
            MIX_L(a0, xl.x, Wsb[7][0]); MIX_H(a1, xl.x, Wsb[7][1]);
            MIX_L(a2, xl.y, Wsb[7][2]); MIX_H(a3, xl.y, Wsb[7][3]);
            MIX_L(a0, xr.x, Wsp[7][0]); MIX_H(a1, xr.x, Wsp[7][1]);
            MIX_L(a2, xr.y, Wsp[7][2]); MIX_H(a3, xr.y, Wsp[7][3]);
            #pragma unroll
            for (int j = 0; j <= 6; ++j) {
                const int d = 512 >> j;
                const i2 xm = *(const i2*)&row[(s0 >= d)        ? s0 - d : 0];
                const i2 xp = *(const i2*)&row[(s0 + d <= 1020) ? s0 + d : 1020];
                MIX_L(a0, xm.x, Wsb[j][0]); MIX_H(a1, xm.x, Wsb[j][1]);
                MIX_L(a2, xm.y, Wsb[j][2]); MIX_H(a3, xm.y, Wsb[j][3]);
                MIX_L(a0, xp.x, Wsp[j][0]); MIX_H(a1, xp.x, Wsp[j][1]);
                MIX_L(a2, xp.y, Wsp[j][2]); MIX_H(a3, xp.y, Wsp[j][3]);
            }

            if (last) {
                *(float4*)(out + (rowbase + r) * SIZE + s0) =
                    make_float4(a0, a1, a2, a3);
            } else {
                f16x4 hv;
                hv[0] = (f16)a0; hv[1] = (f16)a1; hv[2] = (f16)a2; hv[3] = (f16)a3;
                *(f16x4*)&buf[cur ^ 1][r][s0] = hv;
            }
        }
        __syncthreads();
        cur ^= 1;
    }
}

extern "C" void kernel_launch(void* const* d_in, const int* in_sizes, int n_in,
                              void* d_out, int out_size, void* d_ws, size_t ws_size,
                              hipStream_t stream) {
    const float* x      = (const float*)d_in[0];
    const float* diag   = (const float*)d_in[1];
    const float* subpad = (const float*)d_in[2];
    const float* suppad = (const float*)d_in[3];
    const float* logit  = (const float*)d_in[4];
    float* outp = (float*)d_out;

    const int batch = in_sizes[0] / SIZE;                        // 8192
    const size_t needG  = (size_t)SIZE * SIZE * sizeof(float);   // 4 MB
    const size_t needGt = (size_t)SIZE * SIZE * sizeof(f16);     // 2 MB
    const size_t needXh = (size_t)batch * SIZE * sizeof(f16);    // 16 MB

    if (d_ws != nullptr && ws_size >= needG + needGt + needXh) {
        float* G  = (float*)d_ws;
        f16*   Gt = (f16*)((char*)d_ws + needG);
        f16*   xh = (f16*)((char*)d_ws + needG + needGt);
        precompute_G<<<dim3(SIZE / 2), dim3(256), 0, stream>>>(
            diag, subpad, suppad, logit, G);
        transpose_cast<<<dim3(16, 16), dim3(256), 0, stream>>>(G, Gt);
        cvt_x<<<dim3((int)(((long)batch * SIZE) / (256 * 16))), dim3(256), 0, stream>>>(x, xh);
        const int nblocks = (batch / BMT) * (SIZE / BNT);        // 512
        gemm_f16<<<dim3(nblocks), dim3(256), 0, stream>>>(xh, Gt, outp);
    } else {
        butterfly_h16mix<<<dim3(batch / RPB), dim3(256), 0, stream>>>(
            x, diag, subpad, suppad, logit, outp);
    }
}

// Round 13
// 82.027 us; speedup vs baseline: 1.5405x; 1.0654x over previous
//
#include <hip/hip_runtime.h>

#define SIZE 1024
#define MM 10
#define NTERMS 10

typedef _Float16 f16;
typedef __attribute__((ext_vector_type(8))) _Float16 f16x8;
typedef __attribute__((ext_vector_type(4))) _Float16 f16x4;
typedef __attribute__((ext_vector_type(4))) float    f32x4;
typedef __attribute__((ext_vector_type(2))) int      i2;

typedef const __attribute__((address_space(1))) _Float16 gf16;  // global
typedef __attribute__((address_space(3))) _Float16 sf16;        // LDS

__device__ __forceinline__ float4 ldq(const float* p) { return *(const float4*)p; }

#define FMA4F(W, v0, v1, v2, v3)                                     \
    a0 = fmaf((W)[0], (v0), a0); a1 = fmaf((W)[1], (v1), a1);        \
    a2 = fmaf((W)[2], (v2), a2); a3 = fmaf((W)[3], (v3), a3);

__device__ __forceinline__ void cvt16(const float4& v0, const float4& v1, f16x8& h) {
    h[0] = (f16)v0.x; h[1] = (f16)v0.y; h[2] = (f16)v0.z; h[3] = (f16)v0.w;
    h[4] = (f16)v1.x; h[5] = (f16)v1.y; h[6] = (f16)v1.z; h[7] = (f16)v1.w;
}

// ===========================================================================
// Fused pre-pass (R13):
//  blocks 0..511    : precompute Gt = f16(A^T) directly — the R7-proven 512x2
//                     identity-evolution stencil, final write transposed+cast
//                     from registers (G fp32 buffer + transpose kernel DELETED;
//                     same values -> bitwise-identical Gt).
//  blocks 512..2559 : cvt_x (xh = f16(x)) — independent, fills idle CUs
//                     while the precompute blocks sit on coef-load latency.
// ===========================================================================
__global__ __launch_bounds__(256, 2)
void fused_pre(const float* __restrict__ x,
               const float* __restrict__ diag,
               const float* __restrict__ subpad,
               const float* __restrict__ suppad,
               const float* __restrict__ logit,
               f16* __restrict__ Gt,
               f16* __restrict__ xh)
{
    __shared__ float buf[2][2][SIZE];     // 16 KB (precompute branch only)

    const int tid = threadIdx.x;

    if (blockIdx.x >= 512) {
        // ---- cvt_x branch ----
        const long i = ((long)(blockIdx.x - 512) * 256 + tid) * 16;
        const float4 a = ldq(x + i), b = ldq(x + i + 4),
                     c = ldq(x + i + 8), d = ldq(x + i + 12);
        f16x8 h0, h1; cvt16(a, b, h0); cvt16(c, d, h1);
        *(f16x8*)(xh + i)     = h0;
        *(f16x8*)(xh + i + 8) = h1;
        return;
    }

    // ---- precompute branch (R7-proven 512x2 structure) ----
    const int s0  = tid * 4;
    const int rowbase = blockIdx.x * 2;

    #pragma unroll
    for (int r = 0; r < 2; ++r) {
        float4 v;
        v.x = (rowbase + r == s0 + 0) ? 1.f : 0.f;
        v.y = (rowbase + r == s0 + 1) ? 1.f : 0.f;
        v.z = (rowbase + r == s0 + 2) ? 1.f : 0.f;
        v.w = (rowbase + r == s0 + 3) ? 1.f : 0.f;
        *(float4*)&buf[0][r][s0] = v;
    }
    __syncthreads();

    int cur = 0;
    for (int t = 0; t < NTERMS; ++t) {
        const int i = NTERMS - 1 - t;

        float lg[MM];
        float mx = -3.4e38f;
        #pragma unroll
        for (int j = 0; j < MM; ++j) { lg[j] = logit[i * MM + j]; mx = fmaxf(mx, lg[j]); }
        float ssum = 0.f;
        #pragma unroll
        for (int j = 0; j < MM; ++j) { lg[j] = __expf(lg[j] - mx); ssum += lg[j]; }
        const float inv = 1.0f / ssum;

        float D[4] = {0.f, 0.f, 0.f, 0.f};
        float Wsb[MM][4], Wsp[MM][4];
        #pragma unroll
        for (int j = 0; j < MM; ++j) {
            const float pj = lg[j] * inv;
            const float4 dg = ldq(diag   + j * SIZE + s0);
            const float4 sb = ldq(subpad + j * SIZE + s0);
            const float4 sp = ldq(suppad + j * SIZE + s0);
            D[0] = fmaf(pj, dg.x, D[0]); D[1] = fmaf(pj, dg.y, D[1]);
            D[2] = fmaf(pj, dg.z, D[2]); D[3] = fmaf(pj, dg.w, D[3]);
            Wsb[j][0] = pj * sb.x; Wsb[j][1] = pj * sb.y;
            Wsb[j][2] = pj * sb.z; Wsb[j][3] = pj * sb.w;
            Wsp[j][0] = pj * sp.x; Wsp[j][1] = pj * sp.y;
            Wsp[j][2] = pj * sp.z; Wsp[j][3] = pj * sp.w;
        }

        const bool last = (t == NTERMS - 1);
        for (int r = 0; r < 2; ++r) {
            const float* row = &buf[cur][r][0];

            const float4 xo = ldq(row + s0);
            float a0 = D[0] * xo.x, a1 = D[1] * xo.y,
                  a2 = D[2] * xo.z, a3 = D[3] * xo.w;

            const float4 xl = ldq(row + (s0 >= 4         ? s0 - 4 : 0));
            const float4 xr = ldq(row + (s0 + 4 <= 1020  ? s0 + 4 : 1020));

            FMA4F(Wsb[9], xl.w, xo.x, xo.y, xo.z)
            FMA4F(Wsp[9], xo.y, xo.z, xo.w, xr.x)
            FMA4F(Wsb[8], xl.z, xl.w, xo.x, xo.y)
            FMA4F(Wsp[8], xo.z, xo.w, xr.x, xr.y)
            FMA4F(Wsb[7], xl.x, xl.y, xl.z, xl.w)
            FMA4F(Wsp[7], xr.x, xr.y, xr.z, xr.w)
            #pragma unroll
            for (int j = 0; j <= 6; ++j) {
                const int d = 512 >> j;
                const float4 xm = ldq(row + (s0 >= d        ? s0 - d : 0));
                const float4 xp = ldq(row + (s0 + d <= 1020 ? s0 + d : 1020));
                FMA4F(Wsb[j], xm.x, xm.y, xm.z, xm.w)
                FMA4F(Wsp[j], xp.x, xp.y, xp.z, xp.w)
            }

            if (last) {
                // direct transposed f16 store: Gt[s][k] = (f16) G[k][s]
                const int k = rowbase + r;
                Gt[(long)(s0 + 0) * SIZE + k] = (f16)a0;
                Gt[(long)(s0 + 1) * SIZE + k] = (f16)a1;
                Gt[(long)(s0 + 2) * SIZE + k] = (f16)a2;
                Gt[(long)(s0 + 3) * SIZE + k] = (f16)a3;
            } else {
                *(float4*)&buf[cur ^ 1][r][s0] = make_float4(a0, a1, a2, a3);
            }
        }
        __syncthreads();
        cur ^= 1;
    }
}

// ===========================================================================
// GEMM (R13): 1-wave blocks, 64x64 tile. Same inner loop as R12's proven
// gload_lds kernel (B-from-global regs, 16 MFMA/kt, 2-barrier K-loop), but:
//  * grid 128x16 = 2048 blocks = 8 INDEPENDENT waves/CU (R12 had 512 blocks
//    = 2 barrier-groups/CU — grid-starved, MfmaUtil 13%).
//  * __syncthreads in a 1-wave block drains only this wave's own DMA: the
//    cross-wave barrier coupling is gone; 8 waves/CU hide each other's
//    per-kt L2 latency.
//  * bm = bid & 127 (128%8==0): blocks sharing an x-panel stay on one XCD.
// Same MFMA order/values as R12 -> absmax exactly 0.0625.
// ===========================================================================
#define NKT 32

__global__ __launch_bounds__(64)
void gemm64(const f16* __restrict__ xh,
            const f16* __restrict__ Gt,
            float* __restrict__ out)
{
    __shared__ f16 Xs[2][64][32];      // 8 KB, linear

    const int lane = threadIdx.x;      // one wave
    const int bm   = blockIdx.x & 127; // 128 M-tiles; same-bm -> same XCD
    const int bn   = blockIdx.x >> 7;  // 16 N-tiles
    const int lr   = lane & 15, lk = lane >> 4;

    // A staging source: issue i stages rows i*16 + (lane>>2), 16B-slot lane&3
    const f16* gsrc = xh + (long)(bm * 64 + (lane >> 2)) * 1024 + (lane & 3) * 8;

    // B frag rows: n = bn*64 + ni*16 + lr, k = lk*8 (+kt*32)
    const f16* gbase = Gt + (long)(bn * 64 + lr) * 1024 + lk * 8;

    f32x4 acc[4][4];
    #pragma unroll
    for (int mi = 0; mi < 4; ++mi)
        #pragma unroll
        for (int ni = 0; ni < 4; ++ni)
            acc[mi][ni] = (f32x4){0.f, 0.f, 0.f, 0.f};

    f16x8 b0, b1, b2, b3;              // B frags (even kt)
    f16x8 c0, c1, c2, c3;              // B frags (odd kt)

#define STAGE(BUF, KT) {                                                      \
        const f16* gp = gsrc + (KT) * 32;                                     \
        sf16* lp = (sf16*)&Xs[BUF][0][0];                                     \
        __builtin_amdgcn_global_load_lds((gf16*)gp,               lp,        16, 0, 0); \
        __builtin_amdgcn_global_load_lds((gf16*)(gp + 16 * 1024), lp +  512, 16, 0, 0); \
        __builtin_amdgcn_global_load_lds((gf16*)(gp + 32 * 1024), lp + 1024, 16, 0, 0); \
        __builtin_amdgcn_global_load_lds((gf16*)(gp + 48 * 1024), lp + 1536, 16, 0, 0); }
#define LOAD_B(B0, B1, B2, B3, KT) {                                  \
        const f16* gp = gbase + (KT) * 32;                            \
        B0 = *(const f16x8*)(gp);                                     \
        B1 = *(const f16x8*)(gp + 16 * 1024);                         \
        B2 = *(const f16x8*)(gp + 32 * 1024);                         \
        B3 = *(const f16x8*)(gp + 48 * 1024); }
#define COMPUTE(BUF, B0, B1, B2, B3) {                                \
        f16x8 a0 = *(const f16x8*)&Xs[BUF][ 0 + lr][lk * 8];          \
        f16x8 a1 = *(const f16x8*)&Xs[BUF][16 + lr][lk * 8];          \
        f16x8 a2 = *(const f16x8*)&Xs[BUF][32 + lr][lk * 8];          \
        f16x8 a3 = *(const f16x8*)&Xs[BUF][48 + lr][lk * 8];          \
        acc[0][0] = __builtin_amdgcn_mfma_f32_16x16x32_f16(a0, B0, acc[0][0], 0, 0, 0); \
        acc[0][1] = __builtin_amdgcn_mfma_f32_16x16x32_f16(a0, B1, acc[0][1], 0, 0, 0); \
        acc[0][2] = __builtin_amdgcn_mfma_f32_16x16x32_f16(a0, B2, acc[0][2], 0, 0, 0); \
        acc[0][3] = __builtin_amdgcn_mfma_f32_16x16x32_f16(a0, B3, acc[0][3], 0, 0, 0); \
        acc[1][0] = __builtin_amdgcn_mfma_f32_16x16x32_f16(a1, B0, acc[1][0], 0, 0, 0); \
        acc[1][1] = __builtin_amdgcn_mfma_f32_16x16x32_f16(a1, B1, acc[1][1], 0, 0, 0); \
        acc[1][2] = __builtin_amdgcn_mfma_f32_16x16x32_f16(a1, B2, acc[1][2], 0, 0, 0); \
        acc[1][3] = __builtin_amdgcn_mfma_f32_16x16x32_f16(a1, B3, acc[1][3], 0, 0, 0); \
        acc[2][0] = __builtin_amdgcn_mfma_f32_16x16x32_f16(a2, B0, acc[2][0], 0, 0, 0); \
        acc[2][1] = __builtin_amdgcn_mfma_f32_16x16x32_f16(a2, B1, acc[2][1], 0, 0, 0); \
        acc[2][2] = __builtin_amdgcn_mfma_f32_16x16x32_f16(a2, B2, acc[2][2], 0, 0, 0); \
        acc[2][3] = __builtin_amdgcn_mfma_f32_16x16x32_f16(a2, B3, acc[2][3], 0, 0, 0); \
        acc[3][0] = __builtin_amdgcn_mfma_f32_16x16x32_f16(a3, B0, acc[3][0], 0, 0, 0); \
        acc[3][1] = __builtin_amdgcn_mfma_f32_16x16x32_f16(a3, B1, acc[3][1], 0, 0, 0); \
        acc[3][2] = __builtin_amdgcn_mfma_f32_16x16x32_f16(a3, B2, acc[3][2], 0, 0, 0); \
        acc[3][3] = __builtin_amdgcn_mfma_f32_16x16x32_f16(a3, B3, acc[3][3], 0, 0, 0); }

    STAGE(0, 0); LOAD_B(b0, b1, b2, b3, 0);
    __syncthreads();

    #pragma unroll 1
    for (int kt2 = 0; kt2 < NKT / 2; ++kt2) {
        const int kt = kt2 * 2;
        STAGE(1, kt + 1);
        LOAD_B(c0, c1, c2, c3, kt + 1);
        COMPUTE(0, b0, b1, b2, b3);
        __syncthreads();
        if (kt2 < NKT / 2 - 1) {
            STAGE(0, kt + 2);
            LOAD_B(b0, b1, b2, b3, kt + 2);
        }
        COMPUTE(1, c0, c1, c2, c3);
        __syncthreads();
    }

    // epilogue: D lane l,q -> row (l>>4)*4+q, col l&15   (R7-verified)
    const long orow0 = (long)bm * 64 + lk * 4;
    const int  ocol0 = bn * 64 + lr;
    #pragma unroll
    for (int mi = 0; mi < 4; ++mi)
        #pragma unroll
        for (int ni = 0; ni < 4; ++ni)
            #pragma unroll
            for (int q = 0; q < 4; ++q)
                out[(orow0 + mi * 16 + q) * 1024 + ocol0 + ni * 16] = acc[mi][ni][q];

#undef STAGE
#undef LOAD_B
#undef COMPUTE
}

// ===========================================================================
// Fallback (ws too small): R6's proven stencil kernel.
// ===========================================================================
#define RPB 16
#define MIX_L(acc, r32, ww) \
    asm("v_fma_mix_f32 %0, %1, %2, %0 op_sel:[0,0,0] op_sel_hi:[1,0,0]" \
        : "+v"(acc) : "v"(r32), "v"(ww))
#define MIX_H(acc, r32, ww) \
    asm("v_fma_mix_f32 %0, %1, %2, %0 op_sel:[1,0,0] op_sel_hi:[1,0,0]" \
        : "+v"(acc) : "v"(r32), "v"(ww))

__global__ __launch_bounds__(256, 2)
void butterfly_h16mix(const float* __restrict__ x,
                      const float* __restrict__ diag,
                      const float* __restrict__ subpad,
                      const float* __restrict__ suppad,
                      const float* __restrict__ logit,
                      float* __restrict__ out)
{
    __shared__ f16 buf[2][RPB][SIZE];
    const int tid = threadIdx.x;
    const int s0  = tid * 4;
    const long rowbase = (long)blockIdx.x * RPB;

    #pragma unroll
    for (int r = 0; r < RPB; ++r) {
        const float4 v = ldq(x + (rowbase + r) * SIZE + s0);
        f16x4 h;
        h[0] = (f16)v.x; h[1] = (f16)v.y; h[2] = (f16)v.z; h[3] = (f16)v.w;
        *(f16x4*)&buf[0][r][s0] = h;
    }
    __syncthreads();

    int cur = 0;
    for (int t = 0; t < NTERMS; ++t) {
        const int i = NTERMS - 1 - t;
        float lg[MM];
        float mx = -3.4e38f;
        #pragma unroll
        for (int j = 0; j < MM; ++j) { lg[j] = logit[i * MM + j]; mx = fmaxf(mx, lg[j]); }
        float ssum = 0.f;
        #pragma unroll
        for (int j = 0; j < MM; ++j) { lg[j] = __expf(lg[j] - mx); ssum += lg[j]; }
        const float inv = 1.0f / ssum;

        float D[4] = {0.f, 0.f, 0.f, 0.f};
        float Wsb[MM][4], Wsp[MM][4];
        #pragma unroll
        for (int j = 0; j < MM; ++j) {
            const float pj = lg[j] * inv;
            const float4 dg = ldq(diag   + j * SIZE + s0);
            const float4 sb = ldq(subpad + j * SIZE + s0);
            const float4 sp = ldq(suppad + j * SIZE + s0);
            D[0] = fmaf(pj, dg.x, D[0]); D[1] = fmaf(pj, dg.y, D[1]);
            D[2] = fmaf(pj, dg.z, D[2]); D[3] = fmaf(pj, dg.w, D[3]);
            Wsb[j][0] = pj * sb.x; Wsb[j][1] = pj * sb.y;
            Wsb[j][2] = pj * sb.z; Wsb[j][3] = pj * sb.w;
            Wsp[j][0] = pj * sp.x; Wsp[j][1] = pj * sp.y;
            Wsp[j][2] = pj * sp.z; Wsp[j][3] = pj * sp.w;
        }

        const bool last = (t == NTERMS - 1);
        for (int r = 0; r < RPB; ++r) {
            const f16* row = &buf[cur][r][0];
            const i2 xo = *(const i2*)&row[s0];
            const i2 xl = *(const i2*)&row[(s0 >= 4)        ? s0 - 4 : 0];
            const i2 xr = *(const i2*)&row[(s0 + 4 <= 1020) ? s0 + 4 : 1020];
            float a0 = 0.f, a1 = 0.f, a2 = 0.f, a3 = 0.f;

            MIX_L(a0, xo.x, D[0]); MIX_H(a1, xo.x, D[1]);
            MIX_L(a2, xo.y, D[2]); MIX_H(a3, xo.y, D[3]);
            MIX_H(a0, xl.y, Wsb[9][0]); MIX_L(a1, xo.x, Wsb[9][1]);
            MIX_H(a2, xo.x, Wsb[9][2]); MIX_L(a3, xo.y, Wsb[9][3]);
            MIX_H(a0, xo.x, Wsp[9][0]); MIX_L(a1, xo.y, Wsp[9][1]);
            MIX_H(a2, xo.y, Wsp[9][2]); MIX_L(a3, xr.x, Wsp[9][3]);
            MIX_L(a0, xl.y, Wsb[8][0]); MIX_H(a1, xl.y, Wsb[8][1]);
            MIX_L(a2, xo.x, Wsb[8][2]); MIX_H(a3, xo.x, Wsb[8][3]);
            MIX_L(a0, xo.y, Wsp[8][0]); MIX_H(a1, xo.y, Wsp[8][1]);
            MIX_L(a2, xr.x, Wsp[8][2]); MIX_H(a3, xr.x, Wsp[8][3]);
            MIX_L(a0, xl.x, Wsb[7][0]); MIX_H(a1, xl.x, Wsb[7][1]);
            MIX_L(a2, xl.y, Wsb[7][2]); MIX_H(a3, xl.y, Wsb[7][3]);
            MIX_L(a0, xr.x, Wsp[7][0]); MIX_H(a1, xr.x, Wsp[7][1]);
            MIX_L(a2, xr.y, Wsp[7][2]); MIX_H(a3, xr.y, Wsp[7][3]);
            #pragma unroll
            for (int j = 0; j <= 6; ++j) {
                const int d = 512 >> j;
                const i2 xm = *(const i2*)&row[(s0 >= d)        ? s0 - d : 0];
                const i2 xp = *(const i2*)&row[(s0 + d <= 1020) ? s0 + d : 1020];
                MIX_L(a0, xm.x, Wsb[j][0]); MIX_H(a1, xm.x, Wsb[j][1]);
                MIX_L(a2, xm.y, Wsb[j][2]); MIX_H(a3, xm.y, Wsb[j][3]);
                MIX_L(a0, xp.x, Wsp[j][0]); MIX_H(a1, xp.x, Wsp[j][1]);
                MIX_L(a2, xp.y, Wsp[j][2]); MIX_H(a3, xp.y, Wsp[j][3]);
            }

            if (last) {
                *(float4*)(out + (rowbase + r) * SIZE + s0) =
                    make_float4(a0, a1, a2, a3);
            } else {
                f16x4 hv;
                hv[0] = (f16)a0; hv[1] = (f16)a1; hv[2] = (f16)a2; hv[3] = (f16)a3;
                *(f16x4*)&buf[cur ^ 1][r][s0] = hv;
            }
        }
        __syncthreads();
        cur ^= 1;
    }
}

extern "C" void kernel_launch(void* const* d_in, const int* in_sizes, int n_in,
                              void* d_out, int out_size, void* d_ws, size_t ws_size,
                              hipStream_t stream) {
    const float* x      = (const float*)d_in[0];
    const float* diag   = (const float*)d_in[1];
    const float* subpad = (const float*)d_in[2];
    const float* suppad = (const float*)d_in[3];
    const float* logit  = (const float*)d_in[4];
    float* outp = (float*)d_out;

    const int batch = in_sizes[0] / SIZE;                        // 8192
    const size_t needGt = (size_t)SIZE * SIZE * sizeof(f16);     // 2 MB
    const size_t needXh = (size_t)batch * SIZE * sizeof(f16);    // 16 MB

    if (d_ws != nullptr && ws_size >= needGt + needXh) {
        f16* Gt = (f16*)d_ws;
        f16* xh = (f16*)((char*)d_ws + needGt);
        const int cvtBlocks = (int)(((long)batch * SIZE) / (256 * 16));  // 2048
        fused_pre<<<dim3(512 + cvtBlocks), dim3(256), 0, stream>>>(
            x, diag, subpad, suppad, logit, Gt, xh);
        const int nblocks = (batch / 64) * (SIZE / 64);          // 128*16 = 2048
        gemm64<<<dim3(nblocks), dim3(64), 0, stream>>>(xh, Gt, outp);
    } else {
        butterfly_h16mix<<<dim3(batch / RPB), dim3(256), 0, stream>>>(
            x, diag, subpad, suppad, logit, outp);
    }
}